// Round 4
// baseline (1460.085 us; speedup 1.0000x reference)
//
#include <hip/hip_runtime.h>
#include <hip/hip_bf16.h>
#include <math.h>

// Dims: E=512 M=1024 T=1024 H=512 V=10000 ; B=16 S=80 L=200 ; K=10

typedef __bf16 bf16x8 __attribute__((ext_vector_type(8)));
typedef float f32x4 __attribute__((ext_vector_type(4)));
typedef unsigned short u16x8 __attribute__((ext_vector_type(8)));

__device__ inline unsigned short f2b(float f){
  union { float f; unsigned u; } v; v.f = f;
  unsigned u = v.u;
  u += 0x7fff + ((u >> 16) & 1);       // round-to-nearest-even
  return (unsigned short)(u >> 16);
}
__device__ inline float sigm(float x){ return 1.f/(1.f + __expf(-x)); }
__device__ inline float tanh_fast(float x){
  // tanh(x) = 1 - 2/(exp(2x)+1); exact at +-inf, ~1e-6 abs err
  float e = __expf(2.f*x);
  return 1.f - 2.f/(e + 1.f);
}
__device__ inline float wred_max(float v){ for (int o=32;o;o>>=1) v = fmaxf(v, __shfl_xor(v,o)); return v; }
__device__ inline float wred_sum(float v){ for (int o=32;o;o>>=1) v += __shfl_xor(v,o); return v; }

__device__ inline float bred_max(float v, float* sm){
  v = wred_max(v);
  int w = threadIdx.x >> 6;
  if ((threadIdx.x & 63) == 0) sm[w] = v;
  __syncthreads();
  v = fmaxf(fmaxf(sm[0], sm[1]), fmaxf(sm[2], sm[3]));
  __syncthreads();
  return v;
}
__device__ inline float bred_sum(float v, float* sm){
  v = wred_sum(v);
  int w = threadIdx.x >> 6;
  if ((threadIdx.x & 63) == 0) sm[w] = v;
  __syncthreads();
  v = sm[0] + sm[1] + sm[2] + sm[3];
  __syncthreads();
  return v;
}

#define GLOAD_LDS16(g, l) __builtin_amdgcn_global_load_lds( \
    (const __attribute__((address_space(1))) void*)(g), \
    (__attribute__((address_space(3))) void*)(l), 16, 0, 0)

// ---------------------------------------------------------------------------
// f32 -> bf16 conversion, 8 elems/thread
// ---------------------------------------------------------------------------
__global__ void cvt_bf16_kernel(const float* __restrict__ s, unsigned short* __restrict__ d, int n8){
  int i = blockIdx.x*256 + threadIdx.x;
  if (i >= n8) return;
  float4 a = ((const float4*)s)[i*2];
  float4 b = ((const float4*)s)[i*2+1];
  u16x8 o;
  o[0]=f2b(a.x); o[1]=f2b(a.y); o[2]=f2b(a.z); o[3]=f2b(a.w);
  o[4]=f2b(b.x); o[5]=f2b(b.y); o[6]=f2b(b.z); o[7]=f2b(b.w);
  ((u16x8*)d)[i] = o;
}

__global__ void zero_kernel(int* p, int n){
  int i = blockIdx.x*64 + threadIdx.x;
  if (i < n) p[i] = 0;
}

// ---------------------------------------------------------------------------
// C = A @ B^T + b1 + b2.  A:(R,K) bf16 row-major, B:(N,K) bf16 row-major,
// C:(R,N) f32.  128x128 tile, BK=32, 256 thr (4 waves, 2x2 of 64x64).
// grid = (R/128, ceil(N/128)); R%128==0, K%32==0. global_load_lds staging.
// ---------------------------------------------------------------------------
__global__ __launch_bounds__(256) void gemm_bb_kernel(
    const unsigned short* __restrict__ A, const unsigned short* __restrict__ B,
    const float* __restrict__ bias1, const float* __restrict__ bias2,
    float* __restrict__ C, int N, int K)
{
  __shared__ unsigned short lA[128*32];
  __shared__ unsigned short lB[128*32];
  int tid = threadIdx.x;
  int r0 = blockIdx.x << 7, n0 = blockIdx.y << 7;
  int w = tid >> 6, lane = tid & 63;
  int wr = (w >> 1) << 6, wc = (w & 1) << 6;
  int lm = lane & 15, lq = lane >> 4;
  f32x4 acc[4][4] = {};

  int row0 = tid >> 2, row1 = (tid + 256) >> 2, cc = (tid & 3) << 3;
  const unsigned short* Ag0 = A + (size_t)(r0 + row0)*K + cc;
  const unsigned short* Ag1 = A + (size_t)(r0 + row1)*K + cc;
  int br0 = n0 + row0; if (br0 >= N) br0 = N - 1;
  int br1 = n0 + row1; if (br1 >= N) br1 = N - 1;
  const unsigned short* Bg0 = B + (size_t)br0*K + cc;
  const unsigned short* Bg1 = B + (size_t)br1*K + cc;
  unsigned lb0 = (unsigned)(tid & ~63) * 8;   // u16 index, wave-uniform
  unsigned lb1 = 2048 + lb0;

  for (int k0 = 0; k0 < K; k0 += 32){
    GLOAD_LDS16(Ag0 + k0, &lA[lb0]);
    GLOAD_LDS16(Ag1 + k0, &lA[lb1]);
    GLOAD_LDS16(Bg0 + k0, &lB[lb0]);
    GLOAD_LDS16(Bg1 + k0, &lB[lb1]);
    __syncthreads();
    bf16x8 af[4], bfr[4];
#pragma unroll
    for (int i=0;i<4;i++){
      af[i]  = *(const bf16x8*)&lA[(wr + i*16 + lm)*32 + lq*8];
      bfr[i] = *(const bf16x8*)&lB[(wc + i*16 + lm)*32 + lq*8];
    }
#pragma unroll
    for (int i=0;i<4;i++)
#pragma unroll
      for (int j=0;j<4;j++)
        acc[i][j] = __builtin_amdgcn_mfma_f32_16x16x32_bf16(af[i], bfr[j], acc[i][j], 0, 0, 0);
    __syncthreads();
  }
#pragma unroll
  for (int i=0;i<4;i++){
    int rbase = r0 + wr + i*16 + lq*4;
#pragma unroll
    for (int j=0;j<4;j++){
      int n = n0 + wc + j*16 + lm;
      if (n < N){
        float bv = (bias1 ? bias1[n] : 0.f) + (bias2 ? bias2[n] : 0.f);
#pragma unroll
        for (int rr=0;rr<4;rr++)
          C[(size_t)(rbase + rr)*N + n] = acc[i][j][rr] + bv;
      }
    }
  }
}

// ---------------------------------------------------------------------------
// y = x * softmax(x) over rows of 1024; writes bf16 into out[row*ostride+ooff+i]
// ---------------------------------------------------------------------------
__global__ __launch_bounds__(256) void rowsmx_kernel(const float* __restrict__ X,
    unsigned short* __restrict__ out, int ostride, int ooff)
{
  __shared__ float sm[4];
  int row = blockIdx.x, tid = threadIdx.x;
  const float* xr = X + (size_t)row * 1024;
  float x[4];
#pragma unroll
  for (int j=0;j<4;j++) x[j] = xr[j*256 + tid];
  float m = fmaxf(fmaxf(x[0],x[1]), fmaxf(x[2],x[3]));
  m = bred_max(m, sm);
  float s = 0.f;
#pragma unroll
  for (int j=0;j<4;j++) s += __expf(x[j]-m);
  s = bred_sum(s, sm);
  float inv = 1.f / s;
  unsigned short* o = out + (size_t)row*ostride + ooff;
#pragma unroll
  for (int j=0;j<4;j++) o[j*256 + tid] = f2b(x[j] * (__expf(x[j]-m) * inv));
}

// emb f32 (1280x512) -> bf16 into mm_inp_bf cols [0,512)
__global__ void embcopy_kernel(const float* __restrict__ emb, unsigned short* __restrict__ mmbf){
  int idx = blockIdx.x*256 + threadIdx.x;        // 8-elem chunks
  if (idx >= 1280*64) return;
  int row = idx >> 6, c8 = (idx & 63) << 3;
  const float* s = emb + (size_t)row*512 + c8;
  float4 a = ((const float4*)s)[0], b = ((const float4*)s)[1];
  u16x8 o;
  o[0]=f2b(a.x); o[1]=f2b(a.y); o[2]=f2b(a.z); o[3]=f2b(a.w);
  o[4]=f2b(b.x); o[5]=f2b(b.y); o[6]=f2b(b.z); o[7]=f2b(b.w);
  *(u16x8*)&mmbf[(size_t)row*2560 + c8] = o;
}

// mean_feat (128 rows of 204): cols [0,102)=avgpool(att_tempo), [102,204)=avgpool(att_motion)
__global__ void avgpool_kernel(const float* __restrict__ tempo, const float* __restrict__ motion,
                               float* __restrict__ mf)
{
  int bx = blockIdx.x;          // b*8 + s
  int c = threadIdx.x;
  if (c >= 204) return;
  int b = bx >> 3, s = bx & 7;
  const float* src = (c < 102) ? (tempo  + ((size_t)(b*80 + s*10))*1024 + c*10)
                               : (motion + ((size_t)(b*80 + s*10))*1024 + (c-102)*10);
  float acc = 0.f;
  for (int r=0;r<10;r++){
    const float* p = src + (size_t)r*1024;
#pragma unroll
    for (int cc=0;cc<10;cc++) acc += p[cc];
  }
  mf[bx*204 + c] = acc * 0.01f;
}

// m0 = mean_feat @ Wli^T + bli   (128 x 512, K=204)   fp32
__global__ __launch_bounds__(256) void m0_kernel(const float* __restrict__ mf,
    const float* __restrict__ Wli, const float* __restrict__ bli, float* __restrict__ m0)
{
  __shared__ float rowv[204];
  int bx = blockIdx.x, tid = threadIdx.x;
  if (tid < 204) rowv[tid] = mf[bx*204 + tid];
  __syncthreads();
  for (int c = tid; c < 512; c += 256){
    const float* w = Wli + (size_t)c*204;
    float acc = bli[c];
    for (int k=0;k<204;k++) acc += rowv[k]*w[k];
    m0[bx*512 + c] = acc;
  }
}

// ---------------------------------------------------------------------------
// Persistent fused LSTM: 32 blocks x 256 thr, block j owns units [j*16, j*16+16).
// DATA-AS-FLAG design (r0-r3 lesson: every flag/ack protocol costs 3-4
// serialized fabric round trips per step; data-polling costs ~1):
//  - each step sc has its own write-once h buffer hsteps[sc] (16 batches x
//    128 u64, zeroed per launch). Producers pack 4 bf16 into a u64 and OR
//    bit 0 (LSB of one bf16 mantissa, <=2^-9 relative -- way below tolerance)
//    so every published word is nonzero. A word is either 0 (not ready) or
//    final (single writer, write-once: no ABA, no ordering needed).
//  - consumers poll exactly the 32 words their lane's MFMA fragments need
//    (relaxed agent u64 loads, all 32 in flight per sweep; s_sleep(1)
//    between sweeps). No producer drain, no flag store, no flag poll.
//  - NO __syncthreads / fences in the step loop. Waves drift independently:
//    per-wave gbw scratch, per-thread c_reg, read-only w_lds. Deadlock-free:
//    (block,wave,step) dependency graph is a DAG.
//  - wave w owns MFMA cols c=(g*4+uu) -> all 4 gates of (batch, unit 4w+uu)
//    in one wave: gate transpose intra-wave via per-wave LDS (lgkmcnt only),
//    cell + bf16 pack (2 shfl_xor) + publish intra-wave.
// ---------------------------------------------------------------------------
#define LSTM_NBLK 32
#define HP 520   // padded row stride for w_lds (u16 elems)

__global__ __launch_bounds__(256) void lstm_fused_kernel(
    const float* __restrict__ X1, const float* __restrict__ X2,
    const float* __restrict__ Whh,
    unsigned long long* __restrict__ hsteps,
    float* __restrict__ finalA)
{
  __shared__ unsigned short w_lds[64*HP];   // 66560 B
  __shared__ float gbw[4][16][20];          // 5120 B  [wave][col c][batch+pad]
  int tid = threadIdx.x, j = blockIdx.x;
  int j16 = j*16;
  int lane = tid & 63, w = tid >> 6;
  int lm = lane & 15, lq = lane >> 4;
  int bc = lane >> 2, uu = lane & 3, ul = (w << 2) + uu;   // cell thread: batch bc, unit ul

  // ---- preload Whh slice, f32 -> bf16, once.
  // w_lds row r = w'*16 + c with c = g*4+uu  <->  Whh row g*512 + j16 + 4w' + uu
  for (int i = 0; i < 16; i++){
    int ch = tid + i*256;              // 4096 chunks of 8
    int r = ch >> 6, c8 = (ch & 63) << 3;
    int grow = ((r >> 2) & 3)*512 + j16 + ((r >> 4) << 2) + (r & 3);
    const float* s = Whh + (size_t)grow*512 + c8;
    float4 a = ((const float4*)s)[0], b = ((const float4*)s)[1];
    u16x8 o;
    o[0]=f2b(a.x); o[1]=f2b(a.y); o[2]=f2b(a.z); o[3]=f2b(a.w);
    o[4]=f2b(b.x); o[5]=f2b(b.y); o[6]=f2b(b.z); o[7]=f2b(b.w);
    *(u16x8*)&w_lds[r*HP + c8] = o;
  }
  __syncthreads();   // w_lds visible to all waves (only barrier in the kernel)

  float c_reg = 0.f;
  const int wbase = ((w << 4) + lm)*HP;
  const int hq = lm*128 + (lq << 1);       // u64 index: batch lm row (128 u64), +lq*16B
  int sc = 0;

  union HU { unsigned long long q[2]; bf16x8 h; };

  for (int seg = 0; seg < 2; seg++){
    const float* Xp = seg ? X2 : X1;
    int Tst = seg ? 80 : 8;
    for (int t = 0; t < Tst; t++, sc++){
      bool last = (seg == 1) && (t == Tst - 1);
      // ---- X gate biases: issue loads before the poll (latency hidden) ----
      size_t xrow = ((size_t)bc*Tst + t)*2048 + j16 + ul;
      float xi = Xp[xrow];
      float xf = Xp[xrow + 512];
      float xg = Xp[xrow + 1024];
      float xo = Xp[xrow + 1536];

      HU hf[16];
      if (sc > 0){
        // ---- poll the data words directly (data-as-flag) ----
        const unsigned long long* sp = hsteps + (size_t)sc*2048 + hq;
        for (;;){
#pragma unroll
          for (int i = 0; i < 16; i++){
            hf[i].q[0] = __hip_atomic_load(sp + i*8,     __ATOMIC_RELAXED, __HIP_MEMORY_SCOPE_AGENT);
            hf[i].q[1] = __hip_atomic_load(sp + i*8 + 1, __ATOMIC_RELAXED, __HIP_MEMORY_SCOPE_AGENT);
          }
          bool ok = true;
#pragma unroll
          for (int i = 0; i < 16; i++)
            ok = ok && (hf[i].q[0] != 0ull) && (hf[i].q[1] != 0ull);
          if (ok) break;
          __builtin_amdgcn_s_sleep(1);
        }
      } else {
#pragma unroll
        for (int i = 0; i < 16; i++){ hf[i].q[0] = 0ull; hf[i].q[1] = 0ull; }
      }
      // ---- gates: wave w computes cols (g,4w+uu) for 16 batches; 4 chains ----
      f32x4 a0 = {0.f,0.f,0.f,0.f}, a1 = {0.f,0.f,0.f,0.f};
      f32x4 a2 = {0.f,0.f,0.f,0.f}, a3 = {0.f,0.f,0.f,0.f};
#pragma unroll
      for (int i = 0; i < 16; i += 4){
        bf16x8 w0 = *(const bf16x8*)&w_lds[wbase + ((i    ) << 5) + (lq << 3)];
        bf16x8 w1 = *(const bf16x8*)&w_lds[wbase + ((i + 1) << 5) + (lq << 3)];
        bf16x8 w2 = *(const bf16x8*)&w_lds[wbase + ((i + 2) << 5) + (lq << 3)];
        bf16x8 w3 = *(const bf16x8*)&w_lds[wbase + ((i + 3) << 5) + (lq << 3)];
        a0 = __builtin_amdgcn_mfma_f32_16x16x32_bf16(hf[i    ].h, w0, a0, 0, 0, 0);
        a1 = __builtin_amdgcn_mfma_f32_16x16x32_bf16(hf[i + 1].h, w1, a1, 0, 0, 0);
        a2 = __builtin_amdgcn_mfma_f32_16x16x32_bf16(hf[i + 2].h, w2, a2, 0, 0, 0);
        a3 = __builtin_amdgcn_mfma_f32_16x16x32_bf16(hf[i + 3].h, w3, a3, 0, 0, 0);
      }
      // ---- intra-wave gate transpose via per-wave LDS (same-wave DS FIFO) ----
      *(f32x4*)&gbw[w][lm][lq << 2] = (a0 + a1) + (a2 + a3);
      asm volatile("s_waitcnt lgkmcnt(0)" ::: "memory");
      __builtin_amdgcn_sched_barrier(0);
      float iv = gbw[w][uu     ][bc] + xi;
      float fv = gbw[w][4 + uu ][bc] + xf;
      float gv = gbw[w][8 + uu ][bc] + xg;
      float ov = gbw[w][12 + uu][bc] + xo;
      c_reg = sigm(fv)*c_reg + sigm(iv)*tanh_fast(gv);
      float hn = sigm(ov)*tanh_fast(c_reg);
      if (!last){
        // ---- pack 4 units/batch into u64 via 2 shfl_xor; OR bit0 (nonzero
        //      marker, <=2^-9 relative perturbation); publish write-once ----
        unsigned hv = (unsigned)f2b(hn);
        unsigned p = (hv & 0xffffu) | ((unsigned)__shfl_xor((int)hv, 1) << 16);
        unsigned q = (unsigned)__shfl_xor((int)p, 2);
        if ((lane & 3) == 0){
          unsigned long long v64 = (((unsigned long long)q << 32) | (unsigned long long)p) | 1ull;
          __hip_atomic_store(hsteps + (size_t)(sc + 1)*2048 + (size_t)bc*128 + (j << 2) + w, v64,
                             __ATOMIC_RELAXED, __HIP_MEMORY_SCOPE_AGENT);
        }
      }
      // finalA store: off the cross-block critical path
      if (seg) finalA[(size_t)(bc*80 + t)*2560 + j16 + ul] = tanh_fast(hn);
    }
  }
}

// out[r] = bias[0] + dot(A[r*stride .. +ncols], w)    one wave per row
__global__ void proj_kernel(const float* __restrict__ A, int stride, int ncols,
                            const float* __restrict__ w, const float* __restrict__ bias,
                            float* __restrict__ out)
{
  int r = blockIdx.x, lane = threadIdx.x;
  const float* a = A + (size_t)r * stride;
  float acc = 0.f;
  for (int c = lane; c < ncols; c += 64) acc += a[c]*w[c];
  acc = wred_sum(acc);
  if (lane == 0) out[r] = acc + (bias ? bias[0] : 0.f);
}

// softmax over l of (e[b,s] + f[b,l]) masked by l < lens[b]; rows = b*80+s
__global__ __launch_bounds__(256) void attsmax_kernel(const float* __restrict__ e,
    const float* __restrict__ f, const int* __restrict__ lens, float* __restrict__ w)
{
  __shared__ float sm[4];
  int bx = blockIdx.x;
  int b = bx / 80;
  int tid = threadIdx.x;
  int len = lens[b];
  bool ok = (tid < 200) && (tid < len);
  float val = ok ? (e[bx] + f[b*200 + tid]) : -1e30f;
  float m = bred_max(val, sm);
  float ex = ok ? __expf(val - m) : 0.f;
  float s = bred_sum(ex, sm);
  if (tid < 200) w[(size_t)bx*200 + tid] = ex / s;
}

// out[b, s, :] = sum_l w[b,s,l] * feats[b,l,:]  written into finalA at coloff
__global__ __launch_bounds__(256) void attapply_kernel(const float* __restrict__ w,
    const float* __restrict__ feats, float* __restrict__ finalA, int coloff)
{
  __shared__ float lw[8][200];
  int b = blockIdx.x, sg = blockIdx.y;
  int tid = threadIdx.x;
  for (int i = tid; i < 1600; i += 256){
    int ss = i / 200, l = i - ss*200;
    lw[ss][l] = w[(size_t)(b*80 + sg*8 + ss)*200 + l];
  }
  __syncthreads();
  float4 acc[8];
#pragma unroll
  for (int s=0;s<8;s++) acc[s] = make_float4(0,0,0,0);
  const float* fb = feats + (size_t)b*200*1024 + tid*4;
  for (int l=0;l<200;l++){
    float4 v = *(const float4*)(fb + (size_t)l*1024);
#pragma unroll
    for (int s=0;s<8;s++){
      float wv = lw[s][l];
      acc[s].x += wv*v.x; acc[s].y += wv*v.y; acc[s].z += wv*v.z; acc[s].w += wv*v.w;
    }
  }
#pragma unroll
  for (int s=0;s<8;s++){
    float* o = finalA + (size_t)(b*80 + sg*8 + s)*2560 + coloff + tid*4;
    *(float4*)o = acc[s];
  }
}

// in-place log_softmax over rows of 10000
__global__ __launch_bounds__(256) void logsmax_kernel(float* __restrict__ out)
{
  __shared__ float buf[10000];
  __shared__ float sm[4];
  int row = blockIdx.x, tid = threadIdx.x;
  float* o = out + (size_t)row * 10000;
  float m = -1e30f;
  for (int i = tid; i < 10000; i += 256){ float v = o[i]; buf[i] = v; m = fmaxf(m, v); }
  m = bred_max(m, sm);
  float s = 0.f;
  for (int i = tid; i < 10000; i += 256) s += __expf(buf[i] - m);
  s = bred_sum(s, sm);
  float lse = m + __logf(s);
  for (int i = tid; i < 10000; i += 256) o[i] = buf[i] - lse;
}

// ---------------------------------------------------------------------------
extern "C" void kernel_launch(void* const* d_in, const int* in_sizes, int n_in,
                              void* d_out, int out_size, void* d_ws, size_t ws_size,
                              hipStream_t stream)
{
  const float* mfeat = (const float*)d_in[0];
  const float* tfeat = (const float*)d_in[1];
  const float* attm  = (const float*)d_in[2];
  const float* attt  = (const float*)d_in[3];
  const float* emb   = (const float*)d_in[4];
  const int* lens_m  = (const int*)d_in[5];
  const int* lens_t  = (const int*)d_in[6];
  const float* Wm  = (const float*)d_in[8];
  const float* bm  = (const float*)d_in[9];
  const float* Wt  = (const float*)d_in[10];
  const float* bt  = (const float*)d_in[11];
  const float* Wmm = (const float*)d_in[12];
  const float* bmm = (const float*)d_in[13];
  const float* Wli = (const float*)d_in[14];
  const float* bli = (const float*)d_in[15];
  const float* Wih = (const float*)d_in[16];
  const float* Whh = (const float*)d_in[17];
  const float* bih = (const float*)d_in[18];
  const float* bhh = (const float*)d_in[19];
  const float* Wsm = (const float*)d_in[20];
  const float* bsm = (const float*)d_in[21];
  const float* Wst = (const float*)d_in[22];
  const float* bst = (const float*)d_in[23];
  const float* Wo  = (const float*)d_in[24];
  const float* bo  = (const float*)d_in[25];
  float* out = (float*)d_out;

  char* ws = (char*)d_ws;
  size_t off = 0;
  auto alloc = [&](size_t bytes)->void* {
    void* p = (void*)(ws + off);
    off += (bytes + 255) & ~(size_t)255;
    return p;
  };
  // f32 scratch
  float* finalA = (float*)alloc(1280UL*2560*4);
  float* moutp  = (float*)alloc(1280UL*1024*4);
  float* toutp  = (float*)alloc(1280UL*1024*4);
  float* mm_out = (float*)alloc(1280UL*512*4);
  float* meanf  = (float*)alloc(128UL*204*4);
  float* m0     = (float*)alloc(128UL*512*4);
  float* X1     = (float*)alloc(128UL*2048*4);
  float* X2     = (float*)alloc(1280UL*2048*4);
  float* e_m = (float*)alloc(1280UL*4); float* e_t = (float*)alloc(1280UL*4);
  float* f_m = (float*)alloc(3200UL*4); float* f_t = (float*)alloc(3200UL*4);
  float* w_m = (float*)alloc(1280UL*200*4); float* w_t = (float*)alloc(1280UL*200*4);
  // per-step write-once h buffers: 88 steps x 16 batches x 128 u64 (1.44 MB)
  unsigned long long* hsteps = (unsigned long long*)alloc(88UL*2048*8);
  // bf16 scratch
  unsigned short* attm_bf   = (unsigned short*)alloc(1280UL*1024*2);
  unsigned short* attt_bf   = (unsigned short*)alloc(1280UL*1024*2);
  unsigned short* Wm_bf     = (unsigned short*)alloc(1024UL*1024*2);
  unsigned short* Wt_bf     = (unsigned short*)alloc(1024UL*1024*2);
  unsigned short* Wmm_bf    = (unsigned short*)alloc(512UL*2560*2);
  unsigned short* Wih_bf    = (unsigned short*)alloc(2048UL*512*2);
  unsigned short* Wo_bf     = (unsigned short*)alloc(10000UL*2560*2);
  unsigned short* mm_inp_bf = (unsigned short*)alloc(1280UL*2560*2);
  unsigned short* mm_out_bf = (unsigned short*)alloc(1280UL*512*2);
  unsigned short* m0_bf     = (unsigned short*)alloc(128UL*512*2);
  unsigned short* finalA_bf = (unsigned short*)alloc(1280UL*2560*2);

  auto cvt = [&](const float* s, unsigned short* d, size_t n){
    int n8 = (int)(n/8);
    cvt_bf16_kernel<<<(n8 + 255)/256, 256, 0, stream>>>(s, d, n8);
  };
  // weight + input conversions
  cvt(attm, attm_bf, 1280UL*1024);
  cvt(attt, attt_bf, 1280UL*1024);
  cvt(Wm,  Wm_bf,  1024UL*1024);
  cvt(Wt,  Wt_bf,  1024UL*1024);
  cvt(Wmm, Wmm_bf, 512UL*2560);
  cvt(Wih, Wih_bf, 2048UL*512);
  cvt(Wo,  Wo_bf,  10000UL*2560);
  // zero the per-step h buffers (re-poisoned every launch)
  zero_kernel<<<(88*2048*2 + 63)/64, 64, 0, stream>>>((int*)hsteps, 88*2048*2);

  // temp_mout / temp_tout pre-activations
  gemm_bb_kernel<<<dim3(10, 8), 256, 0, stream>>>(attm_bf, Wm_bf, bm, nullptr, moutp, 1024, 1024);
  gemm_bb_kernel<<<dim3(10, 8), 256, 0, stream>>>(attt_bf, Wt_bf, bt, nullptr, toutp, 1024, 1024);
  // x * softmax(x) -> bf16 straight into mm_inp columns; emb -> cols [0,512)
  rowsmx_kernel<<<1280, 256, 0, stream>>>(moutp, mm_inp_bf, 2560, 1536);
  rowsmx_kernel<<<1280, 256, 0, stream>>>(toutp, mm_inp_bf, 2560, 512);
  embcopy_kernel<<<(1280*64 + 255)/256, 256, 0, stream>>>(emb, mm_inp_bf);
  // mm_out = mm_inp @ Wmm^T + bmm
  gemm_bb_kernel<<<dim3(10, 4), 256, 0, stream>>>(mm_inp_bf, Wmm_bf, bmm, nullptr, mm_out, 512, 2560);
  cvt(mm_out, mm_out_bf, 1280UL*512);
  // avgpool + m0
  avgpool_kernel<<<128, 256, 0, stream>>>(attt, attm, meanf);
  m0_kernel<<<128, 256, 0, stream>>>(meanf, Wli, bli, m0);
  cvt(m0, m0_bf, 128UL*512);
  // gate preactivations (x-part) for both LSTMs
  gemm_bb_kernel<<<dim3(1, 16), 256, 0, stream>>>(m0_bf, Wih_bf, bih, bhh, X1, 2048, 512);
  gemm_bb_kernel<<<dim3(10, 16), 256, 0, stream>>>(mm_out_bf, Wih_bf, bih, bhh, X2, 2048, 512);
  // fused persistent LSTM (8 + 80 steps)
  lstm_fused_kernel<<<LSTM_NBLK, 256, 0, stream>>>(X1, X2, Whh, hsteps, finalA);
  // attention score pieces
  proj_kernel<<<1280, 64, 0, stream>>>(finalA, 2560, 512, Wsm, bsm, e_m);
  proj_kernel<<<3200, 64, 0, stream>>>(mfeat, 1024, 1024, Wsm + 512, nullptr, f_m);
  proj_kernel<<<1280, 64, 0, stream>>>(finalA, 2560, 512, Wst, bst, e_t);
  proj_kernel<<<3200, 64, 0, stream>>>(tfeat, 1024, 1024, Wst + 512, nullptr, f_t);
  attsmax_kernel<<<1280, 256, 0, stream>>>(e_t, f_t, lens_t, w_t);
  attsmax_kernel<<<1280, 256, 0, stream>>>(e_m, f_m, lens_m, w_m);
  // weighted sums into finalA cols: att_t2 -> [512,1536), att_m2 -> [1536,2560)
  attapply_kernel<<<dim3(16,10), 256, 0, stream>>>(w_t, tfeat, finalA, 512);
  attapply_kernel<<<dim3(16,10), 256, 0, stream>>>(w_m, mfeat, finalA, 1536);
  // final = finalA @ Wo^T + bo, then in-place log_softmax
  cvt(finalA, finalA_bf, 1280UL*2560);
  gemm_bb_kernel<<<dim3(10, 79), 256, 0, stream>>>(finalA_bf, Wo_bf, bo, nullptr, out, 10000, 2560);
  logsmax_kernel<<<1280, 256, 0, stream>>>(out);
}

// Round 5
// 1027.841 us; speedup vs baseline: 1.4205x; 1.4205x over previous
//
#include <hip/hip_runtime.h>
#include <hip/hip_bf16.h>
#include <math.h>

// Dims: E=512 M=1024 T=1024 H=512 V=10000 ; B=16 S=80 L=200 ; K=10

typedef __bf16 bf16x8 __attribute__((ext_vector_type(8)));
typedef float f32x4 __attribute__((ext_vector_type(4)));
typedef unsigned short u16x8 __attribute__((ext_vector_type(8)));

__device__ inline unsigned short f2b(float f){
  union { float f; unsigned u; } v; v.f = f;
  unsigned u = v.u;
  u += 0x7fff + ((u >> 16) & 1);       // round-to-nearest-even
  return (unsigned short)(u >> 16);
}
__device__ inline float sigm(float x){ return 1.f/(1.f + __expf(-x)); }
__device__ inline float wred_max(float v){ for (int o=32;o;o>>=1) v = fmaxf(v, __shfl_xor(v,o)); return v; }
__device__ inline float wred_sum(float v){ for (int o=32;o;o>>=1) v += __shfl_xor(v,o); return v; }

__device__ inline float bred_max(float v, float* sm){
  v = wred_max(v);
  int w = threadIdx.x >> 6;
  if ((threadIdx.x & 63) == 0) sm[w] = v;
  __syncthreads();
  v = fmaxf(fmaxf(sm[0], sm[1]), fmaxf(sm[2], sm[3]));
  __syncthreads();
  return v;
}
__device__ inline float bred_sum(float v, float* sm){
  v = wred_sum(v);
  int w = threadIdx.x >> 6;
  if ((threadIdx.x & 63) == 0) sm[w] = v;
  __syncthreads();
  v = sm[0] + sm[1] + sm[2] + sm[3];
  __syncthreads();
  return v;
}

#define GLOAD_LDS16(g, l) __builtin_amdgcn_global_load_lds( \
    (const __attribute__((address_space(1))) void*)(g), \
    (__attribute__((address_space(3))) void*)(l), 16, 0, 0)

// ---------------------------------------------------------------------------
// f32 -> bf16 conversion, 8 elems/thread
// ---------------------------------------------------------------------------
__global__ void cvt_bf16_kernel(const float* __restrict__ s, unsigned short* __restrict__ d, int n8){
  int i = blockIdx.x*256 + threadIdx.x;
  if (i >= n8) return;
  float4 a = ((const float4*)s)[i*2];
  float4 b = ((const float4*)s)[i*2+1];
  u16x8 o;
  o[0]=f2b(a.x); o[1]=f2b(a.y); o[2]=f2b(a.z); o[3]=f2b(a.w);
  o[4]=f2b(b.x); o[5]=f2b(b.y); o[6]=f2b(b.z); o[7]=f2b(b.w);
  ((u16x8*)d)[i] = o;
}

__global__ void zero_kernel(int* p, int n){
  int i = blockIdx.x*64 + threadIdx.x;
  if (i < n) p[i] = 0;
}

// ---------------------------------------------------------------------------
// Shared GEMM body: C = A @ B^T + b1 + b2.  A:(R,K) bf16, B:(N,K) bf16,
// C:(R,N) f32.  128x128 tile, BK=32, 256 thr. global_load_lds staging.
// ---------------------------------------------------------------------------
__device__ __forceinline__ void gemm_body(
    const unsigned short* __restrict__ A, const unsigned short* __restrict__ B,
    const float* __restrict__ bias1, const float* __restrict__ bias2,
    float* __restrict__ C, int N, int K,
    unsigned short* lA, unsigned short* lB)
{
  int tid = threadIdx.x;
  int r0 = blockIdx.x << 7, n0 = blockIdx.y << 7;
  int w = tid >> 6, lane = tid & 63;
  int wr = (w >> 1) << 6, wc = (w & 1) << 6;
  int lm = lane & 15, lq = lane >> 4;
  f32x4 acc[4][4] = {};

  int row0 = tid >> 2, row1 = (tid + 256) >> 2, cc = (tid & 3) << 3;
  const unsigned short* Ag0 = A + (size_t)(r0 + row0)*K + cc;
  const unsigned short* Ag1 = A + (size_t)(r0 + row1)*K + cc;
  int br0 = n0 + row0; if (br0 >= N) br0 = N - 1;
  int br1 = n0 + row1; if (br1 >= N) br1 = N - 1;
  const unsigned short* Bg0 = B + (size_t)br0*K + cc;
  const unsigned short* Bg1 = B + (size_t)br1*K + cc;
  unsigned lb0 = (unsigned)(tid & ~63) * 8;   // u16 index, wave-uniform
  unsigned lb1 = 2048 + lb0;

  for (int k0 = 0; k0 < K; k0 += 32){
    GLOAD_LDS16(Ag0 + k0, &lA[lb0]);
    GLOAD_LDS16(Ag1 + k0, &lA[lb1]);
    GLOAD_LDS16(Bg0 + k0, &lB[lb0]);
    GLOAD_LDS16(Bg1 + k0, &lB[lb1]);
    __syncthreads();
    bf16x8 af[4], bfr[4];
#pragma unroll
    for (int i=0;i<4;i++){
      af[i]  = *(const bf16x8*)&lA[(wr + i*16 + lm)*32 + lq*8];
      bfr[i] = *(const bf16x8*)&lB[(wc + i*16 + lm)*32 + lq*8];
    }
#pragma unroll
    for (int i=0;i<4;i++)
#pragma unroll
      for (int j=0;j<4;j++)
        acc[i][j] = __builtin_amdgcn_mfma_f32_16x16x32_bf16(af[i], bfr[j], acc[i][j], 0, 0, 0);
    __syncthreads();
  }
#pragma unroll
  for (int i=0;i<4;i++){
    int rbase = r0 + wr + i*16 + lq*4;
#pragma unroll
    for (int j=0;j<4;j++){
      int n = n0 + wc + j*16 + lm;
      if (n < N){
        float bv = (bias1 ? bias1[n] : 0.f) + (bias2 ? bias2[n] : 0.f);
#pragma unroll
        for (int rr=0;rr<4;rr++)
          C[(size_t)(rbase + rr)*N + n] = acc[i][j][rr] + bv;
      }
    }
  }
}

__global__ __launch_bounds__(256) void gemm_bb_kernel(
    const unsigned short* __restrict__ A, const unsigned short* __restrict__ B,
    const float* __restrict__ bias1, const float* __restrict__ bias2,
    float* __restrict__ C, int N, int K)
{
  __shared__ unsigned short lA[128*32];
  __shared__ unsigned short lB[128*32];
  gemm_body(A, B, bias1, bias2, C, N, K, lA, lB);
}

// two same-shape GEMMs in one launch (blockIdx.z selects) -- 2x occupancy
__global__ __launch_bounds__(256) void gemm_bb2_kernel(
    const unsigned short* __restrict__ A0, const unsigned short* __restrict__ B0,
    const float* __restrict__ b0, float* __restrict__ C0,
    const unsigned short* __restrict__ A1, const unsigned short* __restrict__ B1,
    const float* __restrict__ b1, float* __restrict__ C1, int N, int K)
{
  __shared__ unsigned short lA[128*32];
  __shared__ unsigned short lB[128*32];
  if (blockIdx.z == 0) gemm_body(A0, B0, b0, nullptr, C0, N, K, lA, lB);
  else                 gemm_body(A1, B1, b1, nullptr, C1, N, K, lA, lB);
}

// ---------------------------------------------------------------------------
// y = x * softmax(x) over rows of 1024; merged pair: rows [0,1280) from X0 ->
// ooff0, rows [1280,2560) from X1 -> ooff1.  bf16 out at out[r*2560+ooff+i].
// ---------------------------------------------------------------------------
__global__ __launch_bounds__(256) void rowsmx2_kernel(const float* __restrict__ X0,
    const float* __restrict__ X1, unsigned short* __restrict__ out)
{
  __shared__ float sm[4];
  int bx = blockIdx.x, tid = threadIdx.x;
  int row = (bx < 1280) ? bx : bx - 1280;
  const float* xr = ((bx < 1280) ? X0 : X1) + (size_t)row * 1024;
  int ooff = (bx < 1280) ? 1536 : 512;
  float x[4];
#pragma unroll
  for (int j=0;j<4;j++) x[j] = xr[j*256 + tid];
  float m = fmaxf(fmaxf(x[0],x[1]), fmaxf(x[2],x[3]));
  m = bred_max(m, sm);
  float s = 0.f;
#pragma unroll
  for (int j=0;j<4;j++) s += __expf(x[j]-m);
  s = bred_sum(s, sm);
  float inv = 1.f / s;
  unsigned short* o = out + (size_t)row*2560 + ooff;
#pragma unroll
  for (int j=0;j<4;j++) o[j*256 + tid] = f2b(x[j] * (__expf(x[j]-m) * inv));
}

// emb f32 (1280x512) -> bf16 into mm_inp_bf cols [0,512)
__global__ void embcopy_kernel(const float* __restrict__ emb, unsigned short* __restrict__ mmbf){
  int idx = blockIdx.x*256 + threadIdx.x;        // 8-elem chunks
  if (idx >= 1280*64) return;
  int row = idx >> 6, c8 = (idx & 63) << 3;
  const float* s = emb + (size_t)row*512 + c8;
  float4 a = ((const float4*)s)[0], b = ((const float4*)s)[1];
  u16x8 o;
  o[0]=f2b(a.x); o[1]=f2b(a.y); o[2]=f2b(a.z); o[3]=f2b(a.w);
  o[4]=f2b(b.x); o[5]=f2b(b.y); o[6]=f2b(b.z); o[7]=f2b(b.w);
  *(u16x8*)&mmbf[(size_t)row*2560 + c8] = o;
}

// mean_feat (128 rows of 204): cols [0,102)=avgpool(att_tempo), [102,204)=avgpool(att_motion)
__global__ void avgpool_kernel(const float* __restrict__ tempo, const float* __restrict__ motion,
                               float* __restrict__ mf)
{
  int bx = blockIdx.x;          // b*8 + s
  int c = threadIdx.x;
  if (c >= 204) return;
  int b = bx >> 3, s = bx & 7;
  const float* src = (c < 102) ? (tempo  + ((size_t)(b*80 + s*10))*1024 + c*10)
                               : (motion + ((size_t)(b*80 + s*10))*1024 + (c-102)*10);
  float acc = 0.f;
  for (int r=0;r<10;r++){
    const float* p = src + (size_t)r*1024;
#pragma unroll
    for (int cc=0;cc<10;cc++) acc += p[cc];
  }
  mf[bx*204 + c] = acc * 0.01f;
}

// m0 = mean_feat @ Wli^T + bli   (128 x 512, K=204)   fp32
__global__ __launch_bounds__(256) void m0_kernel(const float* __restrict__ mf,
    const float* __restrict__ Wli, const float* __restrict__ bli, float* __restrict__ m0)
{
  __shared__ float rowv[204];
  int bx = blockIdx.x, tid = threadIdx.x;
  if (tid < 204) rowv[tid] = mf[bx*204 + tid];
  __syncthreads();
  for (int c = tid; c < 512; c += 256){
    const float* w = Wli + (size_t)c*204;
    float acc = bli[c];
    for (int k=0;k<204;k++) acc += rowv[k]*w[k];
    m0[bx*512 + c] = acc;
  }
}

// ---------------------------------------------------------------------------
// Persistent fused LSTM -- the round-0 protocol VERBATIM (measured 294 us;
// every redesigned sync protocol in r1/r3/r4 regressed: 3.34 us/step is the
// empirical agent-scope all-to-all floor). One surgical fix: publish stride
// b*64 -> b*128 (u64 row = 512 units), removing the cross-block write race
// and the dropped upper half of h; consumer loads 8 (not 4) u64 chunks.
// PLUS: blocks [32,256) are HELPERS using the otherwise-idle 224 CUs during
// the ~294 us recurrence for LSTM-independent work: Wo f32->bf16 conversion
// (153 MB) and the f_m/f_t attention projections. No interaction with the
// sync protocol.  LSTM writes act into finalA (f32, for e-proj) AND
// finalA_bf (bf16, for the Wo GEMM) -- kills the separate cvt(finalA) pass.
// ---------------------------------------------------------------------------
#define LSTM_NBLK 32
#define HP 520   // padded row stride (u16 elems)

__global__ __launch_bounds__(256) void lstm_fused_kernel(
    const float* __restrict__ X1, const float* __restrict__ X2,
    const float* __restrict__ Whh,
    unsigned long long* __restrict__ hb0, unsigned long long* __restrict__ hb1,
    float* __restrict__ finalA, unsigned short* __restrict__ finalA_bf,
    int* __restrict__ bar,
    const float* __restrict__ Wo, unsigned short* __restrict__ Wo_bf,
    const float* __restrict__ mfeat, const float* __restrict__ tfeat,
    const float* __restrict__ Wsm, const float* __restrict__ Wst,
    float* __restrict__ f_m, float* __restrict__ f_t)
{
  __shared__ unsigned short w_lds[64*HP];   // 66560 B
  __shared__ unsigned short h_lds[16*HP];   // 16640 B
  __shared__ float gb[4][16][16];           // 4096 B
  __shared__ unsigned short hstage[16][16]; // 512 B [batch][unit]
  int tid = threadIdx.x, j = blockIdx.x;

  if (j >= LSTM_NBLK){
    // ---------------- helper blocks: LSTM-independent work ----------------
    int hb = j - LSTM_NBLK;                 // 0..223
    // (a) Wo f32 -> bf16 : 10000*2560/8 = 3,200,000 chunks of 8
    for (int ch = hb*256 + tid; ch < 3200000; ch += 224*256){
      float4 a = ((const float4*)Wo)[ch*2];
      float4 b = ((const float4*)Wo)[ch*2+1];
      u16x8 o;
      o[0]=f2b(a.x); o[1]=f2b(a.y); o[2]=f2b(a.z); o[3]=f2b(a.w);
      o[4]=f2b(b.x); o[5]=f2b(b.y); o[6]=f2b(b.z); o[7]=f2b(b.w);
      ((u16x8*)Wo_bf)[ch] = o;
    }
    // (b) f_m[r] = dot(mfeat[r], Wsm[512:1024)) ; f_t likewise. 6400 wave-rows.
    int wv = hb*4 + (tid >> 6);             // 0..895
    int lane = tid & 63;
    for (int r = wv; r < 6400; r += 896){
      const float* a = (r < 3200) ? (mfeat + (size_t)r*1024) : (tfeat + (size_t)(r-3200)*1024);
      const float* wvec = (r < 3200) ? (Wsm + 512) : (Wst + 512);
      float acc = 0.f;
      for (int c = lane; c < 1024; c += 64) acc += a[c]*wvec[c];
      acc = wred_sum(acc);
      if (lane == 0){ if (r < 3200) f_m[r] = acc; else f_t[r-3200] = acc; }
    }
    return;
  }

  // ---------------- recurrence blocks: round-0 protocol ----------------
  int j16 = j*16;
  int lane = tid & 63, w = tid >> 6;
  int lm = lane & 15, lq = lane >> 4;

  // ---- preload Whh slice (rows g*512 + j16 + u), f32 -> bf16, once ----
  for (int i = 0; i < 16; i++){
    int ch = tid + i*256;              // 4096 chunks of 8
    int r = ch >> 6, c8 = (ch & 63) << 3;
    int grow = (r >> 4)*512 + j16 + (r & 15);
    const float* s = Whh + (size_t)grow*512 + c8;
    float4 a = ((const float4*)s)[0], b = ((const float4*)s)[1];
    u16x8 o;
    o[0]=f2b(a.x); o[1]=f2b(a.y); o[2]=f2b(a.z); o[3]=f2b(a.w);
    o[4]=f2b(b.x); o[5]=f2b(b.y); o[6]=f2b(b.z); o[7]=f2b(b.w);
    *(u16x8*)&w_lds[r*HP + c8] = o;
  }

  float c_reg = 0.f;
  int ul = tid & 15, bb = tid >> 4;
  unsigned long long* hbufs[2] = { hb0, hb1 };
  const int wbase = ((w << 4) + lm)*HP;
  const int abase = lm*HP;
  const int koff = lq << 3;
  int sc = 0;

  for (int seg = 0; seg < 2; seg++){
    const float* Xp = seg ? X2 : X1;
    int Tst = seg ? 80 : 8;
    for (int t = 0; t < Tst; t++){
      // ---- wait for previous step's h to be at the LLC ----
      if (sc > 0){
        if (tid == 0){
          while (__hip_atomic_load(&bar[sc-1], __ATOMIC_RELAXED, __HIP_MEMORY_SCOPE_AGENT) < LSTM_NBLK)
            __builtin_amdgcn_s_sleep(1);
        }
        __syncthreads();
      }
      // ---- X gate biases for this step (independent of h; overlaps h load) ----
      size_t xrow = ((size_t)bb*Tst + t)*2048 + j16 + ul;
      float xi = Xp[xrow];
      float xf = Xp[xrow + 512];
      float xg = Xp[xrow + 1024];
      float xo = Xp[xrow + 1536];
      // ---- load h state into LDS (LLC-coherent atomic loads) ----
      if (sc == 0){
        u16x8 z = {0,0,0,0,0,0,0,0};
        for (int i = tid; i < 1024; i += 256){
          int b = i >> 6, c8 = (i & 63) << 3;
          *(u16x8*)&h_lds[b*HP + c8] = z;
        }
      } else {
        const unsigned long long* src = hbufs[sc & 1];
#pragma unroll
        for (int it = 0; it < 8; it++){
          int i = tid + it*256;               // u64 chunk: b = i>>7, c64 = i&127
          int b = i >> 7, c64 = i & 127;
          unsigned long long v = __hip_atomic_load(&src[i], __ATOMIC_RELAXED, __HIP_MEMORY_SCOPE_AGENT);
          *(unsigned long long*)&h_lds[b*HP + (c64 << 2)] = v;
        }
      }
      __syncthreads();
      // ---- gates: wave w computes gate w for 16 units x 16 batches ----
      f32x4 a0 = {0.f,0.f,0.f,0.f}, a1 = {0.f,0.f,0.f,0.f};
#pragma unroll
      for (int k0 = 0; k0 < 512; k0 += 64){
        bf16x8 ha = *(const bf16x8*)&h_lds[abase + k0 + koff];
        bf16x8 wa = *(const bf16x8*)&w_lds[wbase + k0 + koff];
        a0 = __builtin_amdgcn_mfma_f32_16x16x32_bf16(ha, wa, a0, 0, 0, 0);
        bf16x8 hbf = *(const bf16x8*)&h_lds[abase + k0 + 32 + koff];
        bf16x8 wbf = *(const bf16x8*)&w_lds[wbase + k0 + 32 + koff];
        a1 = __builtin_amdgcn_mfma_f32_16x16x32_bf16(hbf, wbf, a1, 0, 0, 0);
      }
      f32x4 acc = a0 + a1;
      *(f32x4*)&gb[w][lm][lq << 2] = acc;   // gb[gate][unit][batch]
      __syncthreads();
      // ---- cell update: thread = (batch bb, unit ul) ----
      float iv = gb[0][ul][bb] + xi;
      float fv = gb[1][ul][bb] + xf;
      float gv = gb[2][ul][bb] + xg;
      float ov = gb[3][ul][bb] + xo;
      c_reg = sigm(fv)*c_reg + sigm(iv)*tanhf(gv);
      float hn = sigm(ov)*tanhf(c_reg);
      hstage[bb][ul] = f2b(hn);
      if (seg){
        float act = tanhf(hn);
        size_t fo = (size_t)(bb*80 + t)*2560 + j16 + ul;
        finalA[fo] = act;
        finalA_bf[fo] = f2b(act);
      }
      __syncthreads();
      // ---- publish h slice to LLC (wave 0: 64 x 8B coherent stores) ----
      if (tid < 64){
        int b = tid >> 2, ch = tid & 3;
        unsigned long long v = *(const unsigned long long*)&hstage[b][ch << 2];
        unsigned long long* dst = hbufs[(sc + 1) & 1] + (size_t)b*128 + (j << 2) + ch;
        __hip_atomic_store(dst, v, __ATOMIC_RELAXED, __HIP_MEMORY_SCOPE_AGENT);
      }
      sc++;
      __syncthreads();   // compiler emits s_waitcnt vmcnt(0) before s_barrier -> stores at LLC
      if (tid == 0)
        __hip_atomic_fetch_add(&bar[sc-1], 1, __ATOMIC_RELAXED, __HIP_MEMORY_SCOPE_AGENT);
    }
  }
}

// out[r] = bias[0] + dot(A[r*stride .. +ncols], w)    one wave per row
__global__ void proj_kernel(const float* __restrict__ A, int stride, int ncols,
                            const float* __restrict__ w, const float* __restrict__ bias,
                            float* __restrict__ out)
{
  int r = blockIdx.x, lane = threadIdx.x;
  const float* a = A + (size_t)r * stride;
  float acc = 0.f;
  for (int c = lane; c < ncols; c += 64) acc += a[c]*w[c];
  acc = wred_sum(acc);
  if (lane == 0) out[r] = acc + (bias ? bias[0] : 0.f);
}

// softmax over l of (e[b,s] + f[b,l]) masked by l < lens[b]; rows = b*80+s
__global__ __launch_bounds__(256) void attsmax_kernel(const float* __restrict__ e,
    const float* __restrict__ f, const int* __restrict__ lens, float* __restrict__ w)
{
  __shared__ float sm[4];
  int bx = blockIdx.x;
  int b = bx / 80;
  int tid = threadIdx.x;
  int len = lens[b];
  bool ok = (tid < 200) && (tid < len);
  float val = ok ? (e[bx] + f[b*200 + tid]) : -1e30f;
  float m = bred_max(val, sm);
  float ex = ok ? __expf(val - m) : 0.f;
  float s = bred_sum(ex, sm);
  if (tid < 200) w[(size_t)bx*200 + tid] = ex / s;
}

// out[b, s, :] = sum_l w[b,s,l] * feats[b,l,:]  written as bf16 into
// finalA_bf at coloff (only the Wo GEMM consumes these columns)
__global__ __launch_bounds__(256) void attapply_kernel(const float* __restrict__ w,
    const float* __restrict__ feats, unsigned short* __restrict__ finalA_bf, int coloff)
{
  __shared__ float lw[8][200];
  int b = blockIdx.x, sg = blockIdx.y;
  int tid = threadIdx.x;
  for (int i = tid; i < 1600; i += 256){
    int ss = i / 200, l = i - ss*200;
    lw[ss][l] = w[(size_t)(b*80 + sg*8 + ss)*200 + l];
  }
  __syncthreads();
  float4 acc[8];
#pragma unroll
  for (int s=0;s<8;s++) acc[s] = make_float4(0,0,0,0);
  const float* fb = feats + (size_t)b*200*1024 + tid*4;
  for (int l=0;l<200;l++){
    float4 v = *(const float4*)(fb + (size_t)l*1024);
#pragma unroll
    for (int s=0;s<8;s++){
      float wv = lw[s][l];
      acc[s].x += wv*v.x; acc[s].y += wv*v.y; acc[s].z += wv*v.z; acc[s].w += wv*v.w;
    }
  }
#pragma unroll
  for (int s=0;s<8;s++){
    ushort4 o;
    o.x = f2b(acc[s].x); o.y = f2b(acc[s].y); o.z = f2b(acc[s].z); o.w = f2b(acc[s].w);
    *(ushort4*)&finalA_bf[(size_t)(b*80 + sg*8 + s)*2560 + coloff + tid*4] = o;
  }
}

// in-place log_softmax over rows of 10000
__global__ __launch_bounds__(256) void logsmax_kernel(float* __restrict__ out)
{
  __shared__ float buf[10000];
  __shared__ float sm[4];
  int row = blockIdx.x, tid = threadIdx.x;
  float* o = out + (size_t)row * 10000;
  float m = -1e30f;
  for (int i = tid; i < 10000; i += 256){ float v = o[i]; buf[i] = v; m = fmaxf(m, v); }
  m = bred_max(m, sm);
  float s = 0.f;
  for (int i = tid; i < 10000; i += 256) s += __expf(buf[i] - m);
  s = bred_sum(s, sm);
  float lse = m + __logf(s);
  for (int i = tid; i < 10000; i += 256) o[i] = buf[i] - lse;
}

// ---------------------------------------------------------------------------
extern "C" void kernel_launch(void* const* d_in, const int* in_sizes, int n_in,
                              void* d_out, int out_size, void* d_ws, size_t ws_size,
                              hipStream_t stream)
{
  const float* mfeat = (const float*)d_in[0];
  const float* tfeat = (const float*)d_in[1];
  const float* attm  = (const float*)d_in[2];
  const float* attt  = (const float*)d_in[3];
  const float* emb   = (const float*)d_in[4];
  const int* lens_m  = (const int*)d_in[5];
  const int* lens_t  = (const int*)d_in[6];
  const float* Wm  = (const float*)d_in[8];
  const float* bm  = (const float*)d_in[9];
  const float* Wt  = (const float*)d_in[10];
  const float* bt  = (const float*)d_in[11];
  const float* Wmm = (const float*)d_in[12];
  const float* bmm = (const float*)d_in[13];
  const float* Wli = (const float*)d_in[14];
  const float* bli = (const float*)d_in[15];
  const float* Wih = (const float*)d_in[16];
  const float* Whh = (const float*)d_in[17];
  const float* bih = (const float*)d_in[18];
  const float* bhh = (const float*)d_in[19];
  const float* Wsm = (const float*)d_in[20];
  const float* bsm = (const float*)d_in[21];
  const float* Wst = (const float*)d_in[22];
  const float* bst = (const float*)d_in[23];
  const float* Wo  = (const float*)d_in[24];
  const float* bo  = (const float*)d_in[25];
  float* out = (float*)d_out;

  char* ws = (char*)d_ws;
  size_t off = 0;
  auto alloc = [&](size_t bytes)->void* {
    void* p = (void*)(ws + off);
    off += (bytes + 255) & ~(size_t)255;
    return p;
  };
  // f32 scratch
  float* finalA = (float*)alloc(1280UL*2560*4);
  float* moutp  = (float*)alloc(1280UL*1024*4);
  float* toutp  = (float*)alloc(1280UL*1024*4);
  float* mm_out = (float*)alloc(1280UL*512*4);
  float* meanf  = (float*)alloc(128UL*204*4);
  float* m0     = (float*)alloc(128UL*512*4);
  float* X1     = (float*)alloc(128UL*2048*4);
  float* X2     = (float*)alloc(1280UL*2048*4);
  float* e_m = (float*)alloc(1280UL*4); float* e_t = (float*)alloc(1280UL*4);
  float* f_m = (float*)alloc(3200UL*4); float* f_t = (float*)alloc(3200UL*4);
  float* w_m = (float*)alloc(1280UL*200*4); float* w_t = (float*)alloc(1280UL*200*4);
  int* bar = (int*)alloc(128*4);
  // bf16 / u64 scratch
  unsigned long long* hbuf0 = (unsigned long long*)alloc(16UL*128*8);
  unsigned long long* hbuf1 = (unsigned long long*)alloc(16UL*128*8);
  unsigned short* attm_bf   = (unsigned short*)alloc(1280UL*1024*2);
  unsigned short* attt_bf   = (unsigned short*)alloc(1280UL*1024*2);
  unsigned short* Wm_bf     = (unsigned short*)alloc(1024UL*1024*2);
  unsigned short* Wt_bf     = (unsigned short*)alloc(1024UL*1024*2);
  unsigned short* Wmm_bf    = (unsigned short*)alloc(512UL*2560*2);
  unsigned short* Wih_bf    = (unsigned short*)alloc(2048UL*512*2);
  unsigned short* Wo_bf     = (unsigned short*)alloc(10000UL*2560*2);
  unsigned short* mm_inp_bf = (unsigned short*)alloc(1280UL*2560*2);
  unsigned short* mm_out_bf = (unsigned short*)alloc(1280UL*512*2);
  unsigned short* m0_bf     = (unsigned short*)alloc(128UL*512*2);
  unsigned short* finalA_bf = (unsigned short*)alloc(1280UL*2560*2);

  auto cvt = [&](const float* s, unsigned short* d, size_t n){
    int n8 = (int)(n/8);
    cvt_bf16_kernel<<<(n8 + 255)/256, 256, 0, stream>>>(s, d, n8);
  };
  // weight + input conversions (Wo converted inside the LSTM dispatch)
  cvt(attm, attm_bf, 1280UL*1024);
  cvt(attt, attt_bf, 1280UL*1024);
  cvt(Wm,  Wm_bf,  1024UL*1024);
  cvt(Wt,  Wt_bf,  1024UL*1024);
  cvt(Wmm, Wmm_bf, 512UL*2560);
  cvt(Wih, Wih_bf, 2048UL*512);
  zero_kernel<<<2, 64, 0, stream>>>(bar, 128);

  // temp_mout / temp_tout pre-activations (one 160-block launch)
  gemm_bb2_kernel<<<dim3(10, 8, 2), 256, 0, stream>>>(
      attm_bf, Wm_bf, bm, moutp, attt_bf, Wt_bf, bt, toutp, 1024, 1024);
  // x * softmax(x) -> bf16 straight into mm_inp columns; emb -> cols [0,512)
  rowsmx2_kernel<<<2560, 256, 0, stream>>>(moutp, toutp, mm_inp_bf);
  embcopy_kernel<<<(1280*64 + 255)/256, 256, 0, stream>>>(emb, mm_inp_bf);
  // mm_out = mm_inp @ Wmm^T + bmm
  gemm_bb_kernel<<<dim3(10, 4), 256, 0, stream>>>(mm_inp_bf, Wmm_bf, bmm, nullptr, mm_out, 512, 2560);
  cvt(mm_out, mm_out_bf, 1280UL*512);
  // avgpool + m0
  avgpool_kernel<<<128, 256, 0, stream>>>(attt, attm, meanf);
  m0_kernel<<<128, 256, 0, stream>>>(meanf, Wli, bli, m0);
  cvt(m0, m0_bf, 128UL*512);
  // gate preactivations (x-part) for both LSTMs
  gemm_bb_kernel<<<dim3(1, 16), 256, 0, stream>>>(m0_bf, Wih_bf, bih, bhh, X1, 2048, 512);
  gemm_bb_kernel<<<dim3(10, 16), 256, 0, stream>>>(mm_out_bf, Wih_bf, bih, bhh, X2, 2048, 512);
  // fused persistent LSTM (8 + 80 steps) + 224 helper blocks (Wo cvt, f_m/f_t)
  lstm_fused_kernel<<<256, 256, 0, stream>>>(X1, X2, Whh, hbuf0, hbuf1,
      finalA, finalA_bf, bar, Wo, Wo_bf, mfeat, tfeat, Wsm, Wst, f_m, f_t);
  // attention score pieces (e depends on finalA)
  proj_kernel<<<1280, 64, 0, stream>>>(finalA, 2560, 512, Wsm, bsm, e_m);
  proj_kernel<<<1280, 64, 0, stream>>>(finalA, 2560, 512, Wst, bst, e_t);
  attsmax_kernel<<<1280, 256, 0, stream>>>(e_t, f_t, lens_t, w_t);
  attsmax_kernel<<<1280, 256, 0, stream>>>(e_m, f_m, lens_m, w_m);
  // weighted sums -> bf16 into finalA_bf cols: att_t2 -> [512,1536), att_m2 -> [1536,2560)
  attapply_kernel<<<dim3(16,10), 256, 0, stream>>>(w_t, tfeat, finalA_bf, 512);
  attapply_kernel<<<dim3(16,10), 256, 0, stream>>>(w_m, mfeat, finalA_bf, 1536);
  // final = finalA @ Wo^T + bo, then in-place log_softmax
  gemm_bb_kernel<<<dim3(10, 79), 256, 0, stream>>>(finalA_bf, Wo_bf, bo, nullptr, out, 10000, 2560);
  logsmax_kernel<<<1280, 256, 0, stream>>>(out);
}

// Round 7
// 925.750 us; speedup vs baseline: 1.5772x; 1.1103x over previous
//
#include <hip/hip_runtime.h>
#include <hip/hip_bf16.h>
#include <math.h>

// Dims: E=512 M=1024 T=1024 H=512 V=10000 ; B=16 S=80 L=200 ; K=10

typedef __bf16 bf16x8 __attribute__((ext_vector_type(8)));
typedef float f32x4 __attribute__((ext_vector_type(4)));
typedef unsigned short u16x8 __attribute__((ext_vector_type(8)));

__device__ inline unsigned short f2b(float f){
  union { float f; unsigned u; } v; v.f = f;
  unsigned u = v.u;
  u += 0x7fff + ((u >> 16) & 1);       // round-to-nearest-even
  return (unsigned short)(u >> 16);
}
__device__ inline float sigm(float x){ return 1.f/(1.f + __expf(-x)); }
__device__ inline float tanh_fast(float x){
  float e = __expf(2.f*x);
  return 1.f - 2.f/(e + 1.f);
}
__device__ inline float wred_max(float v){ for (int o=32;o;o>>=1) v = fmaxf(v, __shfl_xor(v,o)); return v; }
__device__ inline float wred_sum(float v){ for (int o=32;o;o>>=1) v += __shfl_xor(v,o); return v; }

__device__ inline float bred_max(float v, float* sm){
  v = wred_max(v);
  int w = threadIdx.x >> 6;
  if ((threadIdx.x & 63) == 0) sm[w] = v;
  __syncthreads();
  v = fmaxf(fmaxf(sm[0], sm[1]), fmaxf(sm[2], sm[3]));
  __syncthreads();
  return v;
}
__device__ inline float bred_sum(float v, float* sm){
  v = wred_sum(v);
  int w = threadIdx.x >> 6;
  if ((threadIdx.x & 63) == 0) sm[w] = v;
  __syncthreads();
  v = sm[0] + sm[1] + sm[2] + sm[3];
  __syncthreads();
  return v;
}

#define GLOAD_LDS16(g, l) __builtin_amdgcn_global_load_lds( \
    (const __attribute__((address_space(1))) void*)(g), \
    (__attribute__((address_space(3))) void*)(l), 16, 0, 0)

__global__ void zero_kernel(int* p, int n){
  int i = blockIdx.x*64 + threadIdx.x;
  if (i < n) p[i] = 0;
}

// ---------------------------------------------------------------------------
// One fused f32->bf16 conversion pass for all 7 upfront conversions.
// Segments (8-elem chunks): attm 163840 | attt 163840 | Wm 131072 | Wt 131072
// | Wmm 163840 | Wih 131072 | emb 81920 (strided dst into mm_inp cols [0,512))
// total = 966656 chunks = 3776 blocks x 256.
// ---------------------------------------------------------------------------
__global__ void cvt7_kernel(
    const float* __restrict__ attm, const float* __restrict__ attt,
    const float* __restrict__ Wm,   const float* __restrict__ Wt,
    const float* __restrict__ Wmm,  const float* __restrict__ Wih,
    const float* __restrict__ emb,
    unsigned short* __restrict__ attm_bf, unsigned short* __restrict__ attt_bf,
    unsigned short* __restrict__ Wm_bf,   unsigned short* __restrict__ Wt_bf,
    unsigned short* __restrict__ Wmm_bf,  unsigned short* __restrict__ Wih_bf,
    unsigned short* __restrict__ mm_inp_bf)
{
  int i = blockIdx.x*256 + threadIdx.x;
  const float* s; unsigned short* d; int o;
  if (i < 458752){
    if (i < 163840){ s = attm; d = attm_bf; o = i; }
    else if (i < 327680){ s = attt; d = attt_bf; o = i - 163840; }
    else { s = Wm; d = Wm_bf; o = i - 327680; }
  } else if (i < 753664){
    if (i < 589824){ s = Wt; d = Wt_bf; o = i - 458752; }
    else { s = Wmm; d = Wmm_bf; o = i - 589824; }
  } else {
    if (i < 884736){ s = Wih; d = Wih_bf; o = i - 753664; }
    else { s = emb; d = mm_inp_bf; o = i - 884736; }
  }
  f32x4 a = ((const f32x4*)s)[(size_t)o*2];
  f32x4 b = ((const f32x4*)s)[(size_t)o*2+1];
  u16x8 v;
  v[0]=f2b(a[0]); v[1]=f2b(a[1]); v[2]=f2b(a[2]); v[3]=f2b(a[3]);
  v[4]=f2b(b[0]); v[5]=f2b(b[1]); v[6]=f2b(b[2]); v[7]=f2b(b[3]);
  if (i >= 884736){
    int row = o >> 6, c8 = (o & 63) << 3;
    *(u16x8*)&d[(size_t)row*2560 + c8] = v;
  } else {
    ((u16x8*)d)[o] = v;
  }
}

// ---------------------------------------------------------------------------
// Shared GEMM body: C = A @ B^T + b1 + b2.  A:(R,K) bf16, B:(N,K) bf16.
// Output: f32 to C, or bf16 to Cbf if Cbf != nullptr.
// 128x128 tile, BK=32, 256 thr. global_load_lds staging.
// ---------------------------------------------------------------------------
__device__ __forceinline__ void gemm_body(
    const unsigned short* __restrict__ A, const unsigned short* __restrict__ B,
    const float* __restrict__ bias1, const float* __restrict__ bias2,
    float* __restrict__ C, unsigned short* __restrict__ Cbf, int N, int K,
    unsigned short* lA, unsigned short* lB, int r0, int n0)
{
  int tid = threadIdx.x;
  int w = tid >> 6, lane = tid & 63;
  int wr = (w >> 1) << 6, wc = (w & 1) << 6;
  int lm = lane & 15, lq = lane >> 4;
  f32x4 acc[4][4] = {};

  int row0 = tid >> 2, row1 = (tid + 256) >> 2, cc = (tid & 3) << 3;
  const unsigned short* Ag0 = A + (size_t)(r0 + row0)*K + cc;
  const unsigned short* Ag1 = A + (size_t)(r0 + row1)*K + cc;
  int br0 = n0 + row0; if (br0 >= N) br0 = N - 1;
  int br1 = n0 + row1; if (br1 >= N) br1 = N - 1;
  const unsigned short* Bg0 = B + (size_t)br0*K + cc;
  const unsigned short* Bg1 = B + (size_t)br1*K + cc;
  unsigned lb0 = (unsigned)(tid & ~63) * 8;   // u16 index, wave-uniform
  unsigned lb1 = 2048 + lb0;

  for (int k0 = 0; k0 < K; k0 += 32){
    GLOAD_LDS16(Ag0 + k0, &lA[lb0]);
    GLOAD_LDS16(Ag1 + k0, &lA[lb1]);
    GLOAD_LDS16(Bg0 + k0, &lB[lb0]);
    GLOAD_LDS16(Bg1 + k0, &lB[lb1]);
    __syncthreads();
    bf16x8 af[4], bfr[4];
#pragma unroll
    for (int i=0;i<4;i++){
      af[i]  = *(const bf16x8*)&lA[(wr + i*16 + lm)*32 + lq*8];
      bfr[i] = *(const bf16x8*)&lB[(wc + i*16 + lm)*32 + lq*8];
    }
#pragma unroll
    for (int i=0;i<4;i++)
#pragma unroll
      for (int j=0;j<4;j++)
        acc[i][j] = __builtin_amdgcn_mfma_f32_16x16x32_bf16(af[i], bfr[j], acc[i][j], 0, 0, 0);
    __syncthreads();
  }
#pragma unroll
  for (int i=0;i<4;i++){
    int rbase = r0 + wr + i*16 + lq*4;
#pragma unroll
    for (int j=0;j<4;j++){
      int n = n0 + wc + j*16 + lm;
      if (n < N){
        float bv = (bias1 ? bias1[n] : 0.f) + (bias2 ? bias2[n] : 0.f);
        if (Cbf){
#pragma unroll
          for (int rr=0;rr<4;rr++)
            Cbf[(size_t)(rbase + rr)*N + n] = f2b(acc[i][j][rr] + bv);
        } else {
#pragma unroll
          for (int rr=0;rr<4;rr++)
            C[(size_t)(rbase + rr)*N + n] = acc[i][j][rr] + bv;
        }
      }
    }
  }
}

__global__ __launch_bounds__(256) void gemm_bb_kernel(
    const unsigned short* __restrict__ A, const unsigned short* __restrict__ B,
    const float* __restrict__ bias1, const float* __restrict__ bias2,
    float* __restrict__ C, unsigned short* __restrict__ Cbf, int N, int K)
{
  __shared__ unsigned short lA[128*32];
  __shared__ unsigned short lB[128*32];
  gemm_body(A, B, bias1, bias2, C, Cbf, N, K, lA, lB, blockIdx.x << 7, blockIdx.y << 7);
}

// two same-shape GEMMs in one launch (blockIdx.z selects)
__global__ __launch_bounds__(256) void gemm_bb2_kernel(
    const unsigned short* __restrict__ A0, const unsigned short* __restrict__ B0,
    const float* __restrict__ b0, float* __restrict__ C0,
    const unsigned short* __restrict__ A1, const unsigned short* __restrict__ B1,
    const float* __restrict__ b1, float* __restrict__ C1, int N, int K)
{
  __shared__ unsigned short lA[128*32];
  __shared__ unsigned short lB[128*32];
  if (blockIdx.z == 0) gemm_body(A0, B0, b0, nullptr, C0, nullptr, N, K, lA, lB, blockIdx.x << 7, blockIdx.y << 7);
  else                 gemm_body(A1, B1, b1, nullptr, C1, nullptr, N, K, lA, lB, blockIdx.x << 7, blockIdx.y << 7);
}

// X1 (128x2048, A=m0_bf) and X2 (1280x2048, A=mm_out_bf) in one launch.
// grid (11,16): x==0 -> X1 tile; x in [1,10] -> X2 row-tile x-1.
__global__ __launch_bounds__(256) void gemm_x12_kernel(
    const unsigned short* __restrict__ m0_bf, const unsigned short* __restrict__ mmo_bf,
    const unsigned short* __restrict__ Wih_bf,
    const float* __restrict__ bih, const float* __restrict__ bhh,
    float* __restrict__ X1, float* __restrict__ X2)
{
  __shared__ unsigned short lA[128*32];
  __shared__ unsigned short lB[128*32];
  if (blockIdx.x == 0)
    gemm_body(m0_bf, Wih_bf, bih, bhh, X1, nullptr, 2048, 512, lA, lB, 0, blockIdx.y << 7);
  else
    gemm_body(mmo_bf, Wih_bf, bih, bhh, X2, nullptr, 2048, 512, lA, lB, (blockIdx.x - 1) << 7, blockIdx.y << 7);
}

// ---------------------------------------------------------------------------
// y = x * softmax(x) over rows of 1024; merged pair -> bf16 into mm_inp cols
// ---------------------------------------------------------------------------
__global__ __launch_bounds__(256) void rowsmx2_kernel(const float* __restrict__ X0,
    const float* __restrict__ X1, unsigned short* __restrict__ out)
{
  __shared__ float sm[4];
  int bx = blockIdx.x, tid = threadIdx.x;
  int row = (bx < 1280) ? bx : bx - 1280;
  const float* xr = ((bx < 1280) ? X0 : X1) + (size_t)row * 1024;
  int ooff = (bx < 1280) ? 1536 : 512;
  float x[4];
#pragma unroll
  for (int j=0;j<4;j++) x[j] = xr[j*256 + tid];
  float m = fmaxf(fmaxf(x[0],x[1]), fmaxf(x[2],x[3]));
  m = bred_max(m, sm);
  float s = 0.f;
#pragma unroll
  for (int j=0;j<4;j++) s += __expf(x[j]-m);
  s = bred_sum(s, sm);
  float inv = 1.f / s;
  unsigned short* o = out + (size_t)row*2560 + ooff;
#pragma unroll
  for (int j=0;j<4;j++) o[j*256 + tid] = f2b(x[j] * (__expf(x[j]-m) * inv));
}

// ---------------------------------------------------------------------------
// fused avgpool (row of 204 means into LDS) + m0 GEMV, writing bf16 directly
// ---------------------------------------------------------------------------
__global__ __launch_bounds__(256) void m0fused_kernel(
    const float* __restrict__ tempo, const float* __restrict__ motion,
    const float* __restrict__ Wli, const float* __restrict__ bli,
    unsigned short* __restrict__ m0_bf)
{
  __shared__ float rowv[204];
  int bx = blockIdx.x, tid = threadIdx.x;
  int b = bx >> 3, s = bx & 7;
  if (tid < 204){
    int c = tid;
    const float* src = (c < 102) ? (tempo  + ((size_t)(b*80 + s*10))*1024 + c*10)
                                 : (motion + ((size_t)(b*80 + s*10))*1024 + (c-102)*10);
    float acc = 0.f;
    for (int r=0;r<10;r++){
      const float* p = src + (size_t)r*1024;
#pragma unroll
      for (int cc=0;cc<10;cc++) acc += p[cc];
    }
    rowv[c] = acc * 0.01f;
  }
  __syncthreads();
  for (int c = tid; c < 512; c += 256){
    const float* w = Wli + (size_t)c*204;
    float acc = bli[c];
    for (int k=0;k<204;k++) acc += rowv[k]*w[k];
    m0_bf[(size_t)bx*512 + c] = f2b(acc);
  }
}

// ---------------------------------------------------------------------------
// Persistent fused LSTM -- round-0 protocol (measured 3.34 us/step floor;
// r1/r3/r4 redesigns all regressed). Publish stride fixed (b*128). Helper
// blocks [32,256) do LSTM-independent streaming; Wo f32 READS are
// NONTEMPORAL so the 102 MB stream does not evict the sync/hbuf LLC lines
// (r5: helpers grew the dispatch 294->380 us; LLC-eviction theory). Wo_bf
// stores stay cached (re-read by the Wo GEMM ~100us later -> LLC hit).
// finalA stores moved AFTER the flag (they were inside the vmcnt(0) drain).
// tanh_fast everywhere (verified r3/r4).
// ---------------------------------------------------------------------------
#define LSTM_NBLK 32
#define HP 520   // padded row stride (u16 elems)

__global__ __launch_bounds__(256) void lstm_fused_kernel(
    const float* __restrict__ X1, const float* __restrict__ X2,
    const float* __restrict__ Whh,
    unsigned long long* __restrict__ hb0, unsigned long long* __restrict__ hb1,
    float* __restrict__ finalA, unsigned short* __restrict__ finalA_bf,
    int* __restrict__ bar,
    const float* __restrict__ Wo, unsigned short* __restrict__ Wo_bf,
    const float* __restrict__ mfeat, const float* __restrict__ tfeat,
    const float* __restrict__ Wsm, const float* __restrict__ Wst,
    float* __restrict__ f_m, float* __restrict__ f_t)
{
  __shared__ unsigned short w_lds[64*HP];   // 66560 B
  __shared__ unsigned short h_lds[16*HP];   // 16640 B
  __shared__ float gb[4][16][16];           // 4096 B
  __shared__ unsigned short hstage[16][16]; // 512 B [batch][unit]
  int tid = threadIdx.x, j = blockIdx.x;

  if (j >= LSTM_NBLK){
    // ---------------- helper blocks: LSTM-independent work ----------------
    int hb = j - LSTM_NBLK;                 // 0..223
    // (a) Wo f32 -> bf16 : nontemporal reads (102 MB, never reused)
    const f32x4* wp = (const f32x4*)Wo;
    for (int ch = hb*256 + tid; ch < 3200000; ch += 224*256){
      f32x4 a = __builtin_nontemporal_load(wp + (size_t)ch*2);
      f32x4 b = __builtin_nontemporal_load(wp + (size_t)ch*2 + 1);
      u16x8 o;
      o[0]=f2b(a[0]); o[1]=f2b(a[1]); o[2]=f2b(a[2]); o[3]=f2b(a[3]);
      o[4]=f2b(b[0]); o[5]=f2b(b[1]); o[6]=f2b(b[2]); o[7]=f2b(b[3]);
      ((u16x8*)Wo_bf)[ch] = o;              // cached: Wo GEMM re-reads from LLC
    }
    // (b) f_m[r] = dot(mfeat[r], Wsm[512:1536)) ; f_t likewise. 6400 wave-rows.
    int wv = hb*4 + (tid >> 6);             // 0..895
    int lane = tid & 63;
    for (int r = wv; r < 6400; r += 896){
      const float* a = (r < 3200) ? (mfeat + (size_t)r*1024) : (tfeat + (size_t)(r-3200)*1024);
      const float* wvec = (r < 3200) ? (Wsm + 512) : (Wst + 512);
      float acc = 0.f;
      for (int c = lane; c < 1024; c += 64) acc += a[c]*wvec[c];
      acc = wred_sum(acc);
      if (lane == 0){ if (r < 3200) f_m[r] = acc; else f_t[r-3200] = acc; }
    }
    return;
  }

  // ---------------- recurrence blocks: round-0 protocol ----------------
  int j16 = j*16;
  int lane = tid & 63, w = tid >> 6;
  int lm = lane & 15, lq = lane >> 4;

  // ---- preload Whh slice (rows g*512 + j16 + u), f32 -> bf16, once ----
  for (int i = 0; i < 16; i++){
    int ch = tid + i*256;              // 4096 chunks of 8
    int r = ch >> 6, c8 = (ch & 63) << 3;
    int grow = (r >> 4)*512 + j16 + (r & 15);
    const float* s = Whh + (size_t)grow*512 + c8;
    f32x4 a = ((const f32x4*)s)[0], b = ((const f32x4*)s)[1];
    u16x8 o;
    o[0]=f2b(a[0]); o[1]=f2b(a[1]); o[2]=f2b(a[2]); o[3]=f2b(a[3]);
    o[4]=f2b(b[0]); o[5]=f2b(b[1]); o[6]=f2b(b[2]); o[7]=f2b(b[3]);
    *(u16x8*)&w_lds[r*HP + c8] = o;
  }

  float c_reg = 0.f;
  int ul = tid & 15, bb = tid >> 4;
  unsigned long long* hbufs[2] = { hb0, hb1 };
  const int wbase = ((w << 4) + lm)*HP;
  const int abase = lm*HP;
  const int koff = lq << 3;
  int sc = 0;

  for (int seg = 0; seg < 2; seg++){
    const float* Xp = seg ? X2 : X1;
    int Tst = seg ? 80 : 8;
    for (int t = 0; t < Tst; t++){
      // ---- wait for previous step's h to be at the LLC ----
      if (sc > 0){
        if (tid == 0){
          while (__hip_atomic_load(&bar[sc-1], __ATOMIC_RELAXED, __HIP_MEMORY_SCOPE_AGENT) < LSTM_NBLK)
            __builtin_amdgcn_s_sleep(1);
        }
        __syncthreads();
      }
      // ---- X gate biases for this step (independent of h; overlaps h load) ----
      size_t xrow = ((size_t)bb*Tst + t)*2048 + j16 + ul;
      float xi = Xp[xrow];
      float xf = Xp[xrow + 512];
      float xg = Xp[xrow + 1024];
      float xo = Xp[xrow + 1536];
      // ---- load h state into LDS (LLC-coherent atomic loads) ----
      if (sc == 0){
        u16x8 z = {0,0,0,0,0,0,0,0};
        for (int i = tid; i < 1024; i += 256){
          int b = i >> 6, c8 = (i & 63) << 3;
          *(u16x8*)&h_lds[b*HP + c8] = z;
        }
      } else {
        const unsigned long long* src = hbufs[sc & 1];
#pragma unroll
        for (int it = 0; it < 8; it++){
          int i = tid + it*256;               // u64 chunk: b = i>>7, c64 = i&127
          int b = i >> 7, c64 = i & 127;
          unsigned long long v = __hip_atomic_load(&src[i], __ATOMIC_RELAXED, __HIP_MEMORY_SCOPE_AGENT);
          *(unsigned long long*)&h_lds[b*HP + (c64 << 2)] = v;
        }
      }
      __syncthreads();
      // ---- gates: wave w computes gate w for 16 units x 16 batches ----
      f32x4 a0 = {0.f,0.f,0.f,0.f}, a1 = {0.f,0.f,0.f,0.f};
#pragma unroll
      for (int k0 = 0; k0 < 512; k0 += 64){
        bf16x8 ha = *(const bf16x8*)&h_lds[abase + k0 + koff];
        bf16x8 wa = *(const bf16x8*)&w_lds[wbase + k0 + koff];
        a0 = __builtin_amdgcn_mfma_f32_16x16x32_bf16(ha, wa, a0, 0, 0, 0);
        bf16x8 hbf = *(const bf16x8*)&h_lds[abase + k0 + 32 + koff];
        bf16x8 wbf = *(const bf16x8*)&w_lds[wbase + k0 + 32 + koff];
        a1 = __builtin_amdgcn_mfma_f32_16x16x32_bf16(hbf, wbf, a1, 0, 0, 0);
      }
      f32x4 acc = a0 + a1;
      *(f32x4*)&gb[w][lm][lq << 2] = acc;   // gb[gate][unit][batch]
      __syncthreads();
      // ---- cell update: thread = (batch bb, unit ul) ----
      float iv = gb[0][ul][bb] + xi;
      float fv = gb[1][ul][bb] + xf;
      float gv = gb[2][ul][bb] + xg;
      float ov = gb[3][ul][bb] + xo;
      c_reg = sigm(fv)*c_reg + sigm(iv)*tanh_fast(gv);
      float hn = sigm(ov)*tanh_fast(c_reg);
      hstage[bb][ul] = f2b(hn);
      __syncthreads();
      // ---- publish h slice to LLC (wave 0: 64 x 8B coherent stores) ----
      if (tid < 64){
        int b = tid >> 2, ch = tid & 3;
        unsigned long long v = *(const unsigned long long*)&hstage[b][ch << 2];
        unsigned long long* dst = hbufs[(sc + 1) & 1] + (size_t)b*128 + (j << 2) + ch;
        __hip_atomic_store(dst, v, __ATOMIC_RELAXED, __HIP_MEMORY_SCOPE_AGENT);
      }
      sc++;
      __syncthreads();   // vmcnt(0) drain: h publish ack'd at LLC
      if (tid == 0)
        __hip_atomic_fetch_add(&bar[sc-1], 1, __ATOMIC_RELAXED, __HIP_MEMORY_SCOPE_AGENT);
      // finalA stores AFTER the flag: off the cross-block critical path
      if (seg){
        float act = tanh_fast(hn);
        size_t fo = (size_t)(bb*80 + t)*2560 + j16 + ul;
        finalA[fo] = act;
        finalA_bf[fo] = f2b(act);
      }
    }
  }
}

// ---------------------------------------------------------------------------
// fused attention scores: e = finalA[:, :512] @ we + b, then masked softmax
// over (e + f).  2560 blocks: [0,1280) -> tempo side, [1280,2560) -> motion.
// ---------------------------------------------------------------------------
__global__ __launch_bounds__(256) void attscore_kernel(const float* __restrict__ finalA,
    const float* __restrict__ Wsm, const float* __restrict__ bsm,
    const float* __restrict__ Wst, const float* __restrict__ bst,
    const float* __restrict__ f_m, const float* __restrict__ f_t,
    const int* __restrict__ lens_m, const int* __restrict__ lens_t,
    float* __restrict__ w_m, float* __restrict__ w_t)
{
  __shared__ float sm[4];
  int bx = blockIdx.x, tid = threadIdx.x;
  bool mside = bx >= 1280;
  int row = mside ? bx - 1280 : bx;
  const float* wv = mside ? Wsm : Wst;
  float bias = (mside ? bsm : bst)[0];
  const float* f = mside ? f_m : f_t;
  const int* lens = mside ? lens_m : lens_t;
  float* w = mside ? w_m : w_t;
  const float* a = finalA + (size_t)row*2560;
  float d = a[tid]*wv[tid] + a[256+tid]*wv[256+tid];
  float e = bred_sum(d, sm) + bias;
  int b = row/80;
  int len = lens[b];
  bool ok = (tid < 200) && (tid < len);
  float val = ok ? (e + f[b*200 + tid]) : -1e30f;
  float m = bred_max(val, sm);
  float ex = ok ? __expf(val - m) : 0.f;
  float s = bred_sum(ex, sm);
  if (tid < 200) w[(size_t)row*200 + tid] = ex / s;
}

// out[b, s, :] = sum_l w[b,s,l] * feats[b,l,:] -> bf16 into finalA_bf.
// grid (16,10,2): z=0 tempo->cols[512,1536), z=1 motion->cols[1536,2560)
__global__ __launch_bounds__(256) void attapply_kernel(
    const float* __restrict__ w_t, const float* __restrict__ w_m,
    const float* __restrict__ tfeat, const float* __restrict__ mfeat,
    unsigned short* __restrict__ finalA_bf)
{
  __shared__ float lw[8][200];
  int b = blockIdx.x, sg = blockIdx.y, z = blockIdx.z;
  const float* w = z ? w_m : w_t;
  const float* feats = z ? mfeat : tfeat;
  int coloff = z ? 1536 : 512;
  int tid = threadIdx.x;
  for (int i = tid; i < 1600; i += 256){
    int ss = i / 200, l = i - ss*200;
    lw[ss][l] = w[(size_t)(b*80 + sg*8 + ss)*200 + l];
  }
  __syncthreads();
  float4 acc[8];
#pragma unroll
  for (int s=0;s<8;s++) acc[s] = make_float4(0,0,0,0);
  const float* fb = feats + (size_t)b*200*1024 + tid*4;
  for (int l=0;l<200;l++){
    float4 v = *(const float4*)(fb + (size_t)l*1024);
#pragma unroll
    for (int s=0;s<8;s++){
      float wv = lw[s][l];
      acc[s].x += wv*v.x; acc[s].y += wv*v.y; acc[s].z += wv*v.z; acc[s].w += wv*v.w;
    }
  }
#pragma unroll
  for (int s=0;s<8;s++){
    ushort4 o;
    o.x = f2b(acc[s].x); o.y = f2b(acc[s].y); o.z = f2b(acc[s].z); o.w = f2b(acc[s].w);
    *(ushort4*)&finalA_bf[(size_t)(b*80 + sg*8 + s)*2560 + coloff + tid*4] = o;
  }
}

// in-place log_softmax over rows of 10000
__global__ __launch_bounds__(256) void logsmax_kernel(float* __restrict__ out)
{
  __shared__ float buf[10000];
  __shared__ float sm[4];
  int row = blockIdx.x, tid = threadIdx.x;
  float* o = out + (size_t)row * 10000;
  float m = -1e30f;
  for (int i = tid; i < 10000; i += 256){ float v = o[i]; buf[i] = v; m = fmaxf(m, v); }
  m = bred_max(m, sm);
  float s = 0.f;
  for (int i = tid; i < 10000; i += 256) s += __expf(buf[i] - m);
  s = bred_sum(s, sm);
  float lse = m + __logf(s);
  for (int i = tid; i < 10000; i += 256) o[i] = buf[i] - lse;
}

// ---------------------------------------------------------------------------
extern "C" void kernel_launch(void* const* d_in, const int* in_sizes, int n_in,
                              void* d_out, int out_size, void* d_ws, size_t ws_size,
                              hipStream_t stream)
{
  const float* mfeat = (const float*)d_in[0];
  const float* tfeat = (const float*)d_in[1];
  const float* attm  = (const float*)d_in[2];
  const float* attt  = (const float*)d_in[3];
  const float* emb   = (const float*)d_in[4];
  const int* lens_m  = (const int*)d_in[5];
  const int* lens_t  = (const int*)d_in[6];
  const float* Wm  = (const float*)d_in[8];
  const float* bm  = (const float*)d_in[9];
  const float* Wt  = (const float*)d_in[10];
  const float* bt  = (const float*)d_in[11];
  const float* Wmm = (const float*)d_in[12];
  const float* bmm = (const float*)d_in[13];
  const float* Wli = (const float*)d_in[14];
  const float* bli = (const float*)d_in[15];
  const float* Wih = (const float*)d_in[16];
  const float* Whh = (const float*)d_in[17];
  const float* bih = (const float*)d_in[18];
  const float* bhh = (const float*)d_in[19];
  const float* Wsm = (const float*)d_in[20];
  const float* bsm = (const float*)d_in[21];
  const float* Wst = (const float*)d_in[22];
  const float* bst = (const float*)d_in[23];
  const float* Wo  = (const float*)d_in[24];
  const float* bo  = (const float*)d_in[25];
  float* out = (float*)d_out;

  char* ws = (char*)d_ws;
  size_t off = 0;
  auto alloc = [&](size_t bytes)->void* {
    void* p = (void*)(ws + off);
    off += (bytes + 255) & ~(size_t)255;
    return p;
  };
  // f32 scratch
  float* finalA = (float*)alloc(1280UL*2560*4);
  float* moutp  = (float*)alloc(1280UL*1024*4);
  float* toutp  = (float*)alloc(1280UL*1024*4);
  float* X1     = (float*)alloc(128UL*2048*4);
  float* X2     = (float*)alloc(1280UL*2048*4);
  float* f_m = (float*)alloc(3200UL*4); float* f_t = (float*)alloc(3200UL*4);
  float* w_m = (float*)alloc(1280UL*200*4); float* w_t = (float*)alloc(1280UL*200*4);
  int* bar = (int*)alloc(128*4);
  // bf16 / u64 scratch
  unsigned long long* hbuf0 = (unsigned long long*)alloc(16UL*128*8);
  unsigned long long* hbuf1 = (unsigned long long*)alloc(16UL*128*8);
  unsigned short* attm_bf   = (unsigned short*)alloc(1280UL*1024*2);
  unsigned short* attt_bf   = (unsigned short*)alloc(1280UL*1024*2);
  unsigned short* Wm_bf     = (unsigned short*)alloc(1024UL*1024*2);
  unsigned short* Wt_bf     = (unsigned short*)alloc(1024UL*1024*2);
  unsigned short* Wmm_bf    = (unsigned short*)alloc(512UL*2560*2);
  unsigned short* Wih_bf    = (unsigned short*)alloc(2048UL*512*2);
  unsigned short* Wo_bf     = (unsigned short*)alloc(10000UL*2560*2);
  unsigned short* mm_inp_bf = (unsigned short*)alloc(1280UL*2560*2);
  unsigned short* mm_out_bf = (unsigned short*)alloc(1280UL*512*2);
  unsigned short* m0_bf     = (unsigned short*)alloc(128UL*512*2);
  unsigned short* finalA_bf = (unsigned short*)alloc(1280UL*2560*2);

  // all upfront f32->bf16 conversions + emb copy in ONE launch
  cvt7_kernel<<<3776, 256, 0, stream>>>(attm, attt, Wm, Wt, Wmm, Wih, emb,
      attm_bf, attt_bf, Wm_bf, Wt_bf, Wmm_bf, Wih_bf, mm_inp_bf);
  zero_kernel<<<2, 64, 0, stream>>>(bar, 128);

  // temp_mout / temp_tout pre-activations (one 160-block launch)
  gemm_bb2_kernel<<<dim3(10, 8, 2), 256, 0, stream>>>(
      attm_bf, Wm_bf, bm, moutp, attt_bf, Wt_bf, bt, toutp, 1024, 1024);
  // x * softmax(x) -> bf16 straight into mm_inp columns
  rowsmx2_kernel<<<2560, 256, 0, stream>>>(moutp, toutp, mm_inp_bf);
  // mm_out = mm_inp @ Wmm^T + bmm  (bf16 output direct)
  gemm_bb_kernel<<<dim3(10, 4), 256, 0, stream>>>(mm_inp_bf, Wmm_bf, bmm, nullptr,
      nullptr, mm_out_bf, 512, 2560);
  // fused avgpool + m0 GEMV (bf16 output direct)
  m0fused_kernel<<<128, 256, 0, stream>>>(attt, attm, Wli, bli, m0_bf);
  // gate preactivations (x-part) for both LSTMs, one launch
  gemm_x12_kernel<<<dim3(11, 16), 256, 0, stream>>>(m0_bf, mm_out_bf, Wih_bf, bih, bhh, X1, X2);
  // fused persistent LSTM (8 + 80 steps) + 224 helper blocks (Wo cvt, f_m/f_t)
  lstm_fused_kernel<<<256, 256, 0, stream>>>(X1, X2, Whh, hbuf0, hbuf1,
      finalA, finalA_bf, bar, Wo, Wo_bf, mfeat, tfeat, Wsm, Wst, f_m, f_t);
  // fused e-projection + masked softmax (both modalities, one launch)
  attscore_kernel<<<2560, 256, 0, stream>>>(finalA, Wsm, bsm, Wst, bst,
      f_m, f_t, lens_m, lens_t, w_m, w_t);
  // weighted sums -> bf16 into finalA_bf cols (both modalities, one launch)
  attapply_kernel<<<dim3(16, 10, 2), 256, 0, stream>>>(w_t, w_m, tfeat, mfeat, finalA_bf);
  // final = finalA @ Wo^T + bo, then in-place log_softmax
  gemm_bb_kernel<<<dim3(10, 79), 256, 0, stream>>>(finalA_bf, Wo_bf, bo, nullptr,
      out, nullptr, 10000, 2560);
  logsmax_kernel<<<1280, 256, 0, stream>>>(out);
}